// Round 4
// baseline (644.476 us; speedup 1.0000x reference)
//
#include <hip/hip_runtime.h>
#include <cstddef>
#include <cstdint>
#include <math.h>

#define N_NODES 50000
#define N_EDGES 1600000
#define IN_C 512
#define HID_C 256
#define OUT_C 50
#define PAD_C 64
#define NUM_LAYERS 10
#define NBUCK 98          // ceil(50000/512) row-buckets
#define BSHIFT 9          // 512 rows per bucket
#define BCAP 20480        // mean 16327 + 32 sigma — overflow unreachable
#define PHB_CHUNK 8192    // edges per block in bucket_scatter
#define PHB_BLOCKS 196    // ceil(N_EDGES / PHB_CHUNK)

typedef __attribute__((ext_vector_type(8))) short short8;    // 8 bf16 (4 VGPRs)
typedef __attribute__((ext_vector_type(4))) float floatx4;   // MFMA C/D frag

__device__ inline unsigned short f2bf(float f) {             // RNE fp32->bf16
    unsigned int u = __float_as_uint(f);
    u += 0x7fffu + ((u >> 16) & 1u);
    return (unsigned short)(u >> 16);
}

__device__ inline unsigned cvtpk(float lo, float hi) {       // 2xf32 -> packed bf16x2 (RNE)
    unsigned r;
    asm("v_cvt_pk_bf16_f32 %0, %1, %2" : "=v"(r) : "v"(lo), "v"(hi));
    return r;
}

__device__ inline short8 pack_bf16x8(float4 lo, float4 hi) {
    union { unsigned u[4]; short8 s; } r;
    r.u[0] = cvtpk(lo.x, lo.y);
    r.u[1] = cvtpk(lo.z, lo.w);
    r.u[2] = cvtpk(hi.x, hi.y);
    r.u[3] = cvtpk(hi.z, hi.w);
    return r.s;
}

// async 16B global->LDS (LDS dest is wave-uniform base + lane*16)
#define ASYNC16(g, l)                                                     \
    __builtin_amdgcn_global_load_lds(                                     \
        (const __attribute__((address_space(1))) void*)(g),               \
        (__attribute__((address_space(3))) void*)(l), 16, 0, 0)

// ---------------------------------------------------------------------------
// W1 [512,256] fp32  ->  Wt [256,512] bf16   (LDS-tiled transpose)
// ---------------------------------------------------------------------------
__global__ __launch_bounds__(256) void transpose_w1(const float* __restrict__ W1,
                                                    unsigned short* __restrict__ Wt) {
    __shared__ float tile[32][33];
    int bx = blockIdx.x;               // k-tile (16)
    int by = blockIdx.y;               // n-tile (8)
    int tx = threadIdx.x & 31, ty = threadIdx.x >> 5;   // 32 x 8
#pragma unroll
    for (int i = 0; i < 32; i += 8)
        tile[ty + i][tx] = W1[(bx * 32 + ty + i) * HID_C + by * 32 + tx];
    __syncthreads();
#pragma unroll
    for (int i = 0; i < 32; i += 8)
        Wt[(size_t)(by * 32 + ty + i) * IN_C + bx * 32 + tx] = f2bf(tile[tx][ty + i]);
}

// ---------------------------------------------------------------------------
// pad_w2: W2 [256,50] fp32 -> Wpt [64,256] bf16 TRANSPOSED, b2 -> bp[64]
// ---------------------------------------------------------------------------
__global__ void pad_w2(const float* __restrict__ W2, const float* __restrict__ b2,
                       unsigned short* __restrict__ Wpt, float* __restrict__ bp) {
    int idx = blockIdx.x * blockDim.x + threadIdx.x;
    if (idx < PAD_C * HID_C) {
        int n = idx >> 8, k = idx & 255;
        float v = (n < OUT_C) ? W2[k * OUT_C + n] : 0.f;
        Wpt[idx] = f2bf(v);
    }
    if (idx < PAD_C) bp[idx] = (idx < OUT_C) ? b2[idx] : 0.f;
}

// ---------------------------------------------------------------------------
// GEMM1+GEMM2 fused v2:
//  * A never touches LDS: each lane global-loads its own MFMA fragment
//    (rows wm+{0,16}+l16, 32B k-window per quad) 1 K-step ahead; packed to
//    bf16 with v_cvt_pk_bf16_f32 (2 instr / 4 elems vs ~12 for bit-twiddle).
//  * B: double-buffered chunk-major LDS via global_load_lds (conflict-free,
//    R2-verified). Only 4 async loads/thread/K-step.
//  * R1-style single __syncthreads per K-step (R2's counted-vmcnt + fences
//    regressed: m141 order-pinning). Compiler schedules freely.
//  * LDS 48 -> 33.8 KB: 4 blocks/CU (was 3).
//  * Epilogue unchanged (R2-verified): relu(h)+b1 -> Hs bf16 -> 32 MFMA vs
//    Wpt -> h0f/h0b. h_hid never exists in HBM.
// ---------------------------------------------------------------------------
__global__ __launch_bounds__(256) void gemm1_fused(const float* __restrict__ A,
                                                   const unsigned short* __restrict__ Wt,
                                                   const float* __restrict__ b1,
                                                   const unsigned short* __restrict__ Wpt,
                                                   const float* __restrict__ bp,
                                                   float* __restrict__ h0f,
                                                   unsigned short* __restrict__ h0b) {
    __shared__ __align__(16) char smem[33792];                 // max(2x16KB B, 64x264x2 Hs)
    unsigned short* Bs0 = (unsigned short*)smem;               // 16 KB
    unsigned short* Bs1 = (unsigned short*)(smem + 16384);     // 16 KB
    unsigned short* Hs  = (unsigned short*)smem;               // [64][264] bf16 (reused)
    const int HS_LD = 264;

    const int tid  = threadIdx.x;
    const int wave = tid >> 6, lane = tid & 63;
    const int quad = lane >> 4, l16 = lane & 15;
    const int m0 = blockIdx.x * 64;
    const int wm = (wave >> 1) * 32;               // row offset of this wave
    const int wn = (wave & 1) * 128;               // col offset of this wave

    floatx4 acc[2][8];
#pragma unroll
    for (int i = 0; i < 2; ++i)
#pragma unroll
        for (int j = 0; j < 8; ++j) acc[i][j] = (floatx4){0.f, 0.f, 0.f, 0.f};

    // per-lane A base pointers (rows clamped; garbage rows masked at writes,
    // and GEMM outputs are row-local so garbage never mixes into valid rows)
    int r0 = m0 + wm + l16;
    int r1 = r0 + 16;
    if (r0 >= N_NODES) r0 = N_NODES - 1;
    if (r1 >= N_NODES) r1 = N_NODES - 1;
    const float* a0 = A + (size_t)r0 * IN_C + (quad << 3);
    const float* a1 = A + (size_t)r1 * IN_C + (quad << 3);

    auto stageB = [&](unsigned short* Bs_, int k0) {
#pragma unroll
        for (int j = 0; j < 4; ++j) {
            const unsigned short* src = Wt + (size_t)tid * IN_C + k0 + (j << 3);
            ASYNC16(src, Bs_ + (j << 11) + (tid << 3));
        }
    };

    float4 pa[4];                                   // A data for CURRENT K-step
    auto loadA = [&](int k0) {
        pa[0] = *(const float4*)(a0 + k0);
        pa[1] = *(const float4*)(a0 + k0 + 4);
        pa[2] = *(const float4*)(a1 + k0);
        pa[3] = *(const float4*)(a1 + k0 + 4);
    };

    auto compute = [&](const unsigned short* Bs_, short8 af0, short8 af1) {
#pragma unroll
        for (int nt = 0; nt < 8; ++nt) {
            short8 bf = *(const short8*)&Bs_[(quad << 11) + ((wn + nt * 16 + l16) << 3)];
            acc[0][nt] = __builtin_amdgcn_mfma_f32_16x16x32_bf16(af0, bf, acc[0][nt], 0, 0, 0);
            acc[1][nt] = __builtin_amdgcn_mfma_f32_16x16x32_bf16(af1, bf, acc[1][nt], 0, 0, 0);
        }
    };

    stageB(Bs0, 0);
    loadA(0);
    __syncthreads();                               // Bs0 + pa landed

    for (int kp = 0; kp < 8; ++kp) {
        const int k0 = kp * 64;
        // ---- step using Bs0 (k = k0) ----
        stageB(Bs1, k0 + 32);                      // async, overlaps MFMA
        {
            short8 af0 = pack_bf16x8(pa[0], pa[1]);
            short8 af1 = pack_bf16x8(pa[2], pa[3]);
            loadA(k0 + 32);                        // next step's A, in flight
            compute(Bs0, af0, af1);
        }
        __syncthreads();                           // Bs1 + pa ready; Bs0 free
        // ---- step using Bs1 (k = k0+32) ----
        if (kp < 7) stageB(Bs0, k0 + 64);
        {
            short8 af0 = pack_bf16x8(pa[0], pa[1]);
            short8 af1 = pack_bf16x8(pa[2], pa[3]);
            if (kp < 7) loadA(k0 + 64);
            compute(Bs1, af0, af1);
        }
        __syncthreads();                           // Bs0 + pa ready; Bs1 free
    }

    // --- stage relu(h + b1) to LDS bf16 (row = quad*4+r, col = l16 map) ----
#pragma unroll
    for (int nt = 0; nt < 8; ++nt) {
        int n = wn + nt * 16 + l16;
        float bn = b1[n];
#pragma unroll
        for (int mt = 0; mt < 2; ++mt)
#pragma unroll
            for (int r = 0; r < 4; ++r) {
                float v = acc[mt][nt][r] + bn;
                v = v > 0.f ? v : 0.f;
                Hs[(wm + mt * 16 + quad * 4 + r) * HS_LD + n] = f2bf(v);
            }
    }
    __syncthreads();

    // --- fused GEMM2: h0[64,64] = Hs[64,256] @ Wpt^T + bp ------------------
    floatx4 acc2[4];
#pragma unroll
    for (int nt = 0; nt < 4; ++nt) acc2[nt] = (floatx4){0.f, 0.f, 0.f, 0.f};
    const int hrow = (wave << 4) + l16;
#pragma unroll
    for (int k2 = 0; k2 < 8; ++k2) {
        short8 haf = *(const short8*)&Hs[hrow * HS_LD + (k2 << 5) + (quad << 3)];
#pragma unroll
        for (int nt = 0; nt < 4; ++nt) {
            short8 bf = *(const short8*)&Wpt[(size_t)((nt << 4) + l16) * HID_C + (k2 << 5) + (quad << 3)];
            acc2[nt] = __builtin_amdgcn_mfma_f32_16x16x32_bf16(haf, bf, acc2[nt], 0, 0, 0);
        }
    }
#pragma unroll
    for (int nt = 0; nt < 4; ++nt) {
        int c = (nt << 4) + l16;
        float bn = bp[c];
#pragma unroll
        for (int r = 0; r < 4; ++r) {
            int row = m0 + (wave << 4) + (quad << 2) + r;
            if (row < N_NODES) {
                float v = acc2[nt][r] + bn;
                h0f[(size_t)row * PAD_C + c] = v;
                h0b[(size_t)row * PAD_C + c] = f2bf(v);
            }
        }
    }
}

// ---------------------------------------------------------------------------
// CSR build v3 (R7-verified): bucket_scatter -> 98-scan -> fused per-bucket
// hist/scan/scatter. No global histogram, no global fill atomics.
// ---------------------------------------------------------------------------
__global__ __launch_bounds__(256) void bucket_scatter(const int* __restrict__ erow,
                                                      const int* __restrict__ ecol,
                                                      const float* __restrict__ ew,
                                                      int* __restrict__ bfill,
                                                      uint2* __restrict__ buckets) {
    __shared__ int lcnt[NBUCK];
    __shared__ int lbase[NBUCK];
    const int t = threadIdx.x;
    for (int b = t; b < NBUCK; b += 256) lcnt[b] = 0;
    __syncthreads();
    const int e0 = blockIdx.x * PHB_CHUNK;
    const int e1 = min(e0 + PHB_CHUNK, N_EDGES);
    for (int e = e0 + t; e < e1; e += 256)
        atomicAdd(&lcnt[erow[e] >> BSHIFT], 1);
    __syncthreads();
    for (int b = t; b < NBUCK; b += 256) {
        lbase[b] = atomicAdd(&bfill[b], lcnt[b]);
        lcnt[b] = 0;
    }
    __syncthreads();
    for (int e = e0 + t; e < e1; e += 256) {
        int r = erow[e];
        int b = r >> BSHIFT;
        int o = atomicAdd(&lcnt[b], 1);
        int idx = lbase[b] + o;
        if (idx < BCAP) {   // BCAP = mean + 32 sigma: always true
            unsigned packed = ((unsigned)(r - (b << BSHIFT)) << 17) | (unsigned)ecol[e];
            buckets[(size_t)b * BCAP + idx] = make_uint2(packed, __float_as_uint(ew[e]));
        }
    }
}

__global__ __launch_bounds__(128) void bucket_scan(const int* __restrict__ bfill,
                                                   int* __restrict__ bbase,
                                                   int* __restrict__ rowptr) {
    __shared__ int sd[128];
    int t = threadIdx.x;
    int v = (t < NBUCK) ? min(bfill[t], BCAP) : 0;
    sd[t] = v;
    __syncthreads();
    for (int off = 1; off < 128; off <<= 1) {
        int x = (t >= off) ? sd[t - off] : 0;
        __syncthreads();
        sd[t] += x;
        __syncthreads();
    }
    if (t < NBUCK) bbase[t] = sd[t] - v;
    if (t == NBUCK - 1) {
        bbase[NBUCK] = sd[t];
        rowptr[N_NODES] = sd[t];
    }
}

__global__ __launch_bounds__(256) void bucket_csr(const uint2* __restrict__ buckets,
                                                  const int* __restrict__ bfill,
                                                  const int* __restrict__ bbase,
                                                  int* __restrict__ rowptr,
                                                  uint2* __restrict__ edges) {
    __shared__ int hist[512];
    __shared__ int excl[512];
    __shared__ int psum[256];
    const int b = blockIdx.x;
    const int t = threadIdx.x;
    const int n = min(bfill[b], BCAP);
    const uint2* bk = buckets + (size_t)b * BCAP;

    hist[t] = 0; hist[t + 256] = 0;
    __syncthreads();
    for (int i = t; i < n; i += 256)
        atomicAdd(&hist[bk[i].x >> 17], 1);
    __syncthreads();
    int a0 = hist[2 * t], a1 = hist[2 * t + 1];
    psum[t] = a0 + a1;
    __syncthreads();
    for (int off = 1; off < 256; off <<= 1) {
        int x = (t >= off) ? psum[t - off] : 0;
        __syncthreads();
        psum[t] += x;
        __syncthreads();
    }
    int pe = psum[t] - (a0 + a1);
    excl[2 * t] = pe;
    excl[2 * t + 1] = pe + a0;
    __syncthreads();
    const int base = bbase[b];
#pragma unroll
    for (int k = 0; k < 2; ++k) {
        int lr = t + k * 256;
        int r = (b << BSHIFT) + lr;
        if (r < N_NODES) rowptr[r] = base + excl[lr];
    }
    hist[t] = 0; hist[t + 256] = 0;
    __syncthreads();
    for (int i = t; i < n; i += 256) {
        uint2 ed = bk[i];
        int lr = ed.x >> 17;
        int pos = base + excl[lr] + atomicAdd(&hist[lr], 1);
        edges[pos] = make_uint2(ed.x & 0x1FFFFu, ed.y);
    }
}

// ---------------------------------------------------------------------------
// Propagation v2: x4 unroll (4 independent 128B gathers in flight; avg deg 32
// = exactly one x4 iter). 8 lanes x 16B cover one 128B row; xor(8/16/32)
// all-reduce; LAST layer fuses log_softmax.
// edge_fma is an inline FUNCTION (R3's macro substituted its 'w' param into
// the '.w' member access -> hv0.w1 compile error).
// ---------------------------------------------------------------------------
__device__ inline void edge_fma(float* acc, float wgt, uint4 hv) {
    acc[0] = fmaf(wgt, __uint_as_float(hv.x << 16),         acc[0]);
    acc[1] = fmaf(wgt, __uint_as_float(hv.x & 0xffff0000u), acc[1]);
    acc[2] = fmaf(wgt, __uint_as_float(hv.y << 16),         acc[2]);
    acc[3] = fmaf(wgt, __uint_as_float(hv.y & 0xffff0000u), acc[3]);
    acc[4] = fmaf(wgt, __uint_as_float(hv.z << 16),         acc[4]);
    acc[5] = fmaf(wgt, __uint_as_float(hv.z & 0xffff0000u), acc[5]);
    acc[6] = fmaf(wgt, __uint_as_float(hv.w << 16),         acc[6]);
    acc[7] = fmaf(wgt, __uint_as_float(hv.w & 0xffff0000u), acc[7]);
}

template <bool LAST>
__global__ __launch_bounds__(256) void prop8(const int* __restrict__ rowptr,
                                             const uint2* __restrict__ edges,
                                             const unsigned short* __restrict__ hin,
                                             const float* __restrict__ h0f,
                                             unsigned short* __restrict__ hout_b,
                                             float* __restrict__ out_f) {
    int wid = (blockIdx.x * blockDim.x + threadIdx.x) >> 6;
    if (wid >= N_NODES) return;
    int lane = threadIdx.x & 63;
    int slot = lane >> 3;
    int lc   = lane & 7;
    int s = rowptr[wid], e = rowptr[wid + 1];

    float acc0[8], acc1[8];
#pragma unroll
    for (int k = 0; k < 8; ++k) { acc0[k] = 0.f; acc1[k] = 0.f; }

    int i = s;
    for (; i + 32 <= e; i += 32) {
        uint2 cw0 = edges[i + slot];
        uint2 cw1 = edges[i + 8 + slot];
        uint2 cw2 = edges[i + 16 + slot];
        uint2 cw3 = edges[i + 24 + slot];
        uint4 hv0 = *(const uint4*)((const char*)hin + ((size_t)cw0.x << 7) + lc * 16);
        uint4 hv1 = *(const uint4*)((const char*)hin + ((size_t)cw1.x << 7) + lc * 16);
        uint4 hv2 = *(const uint4*)((const char*)hin + ((size_t)cw2.x << 7) + lc * 16);
        uint4 hv3 = *(const uint4*)((const char*)hin + ((size_t)cw3.x << 7) + lc * 16);
        edge_fma(acc0, __uint_as_float(cw0.y), hv0);
        edge_fma(acc1, __uint_as_float(cw1.y), hv1);
        edge_fma(acc0, __uint_as_float(cw2.y), hv2);
        edge_fma(acc1, __uint_as_float(cw3.y), hv3);
    }
    for (; i + 16 <= e; i += 16) {
        uint2 cw0 = edges[i + slot];
        uint2 cw1 = edges[i + 8 + slot];
        uint4 hv0 = *(const uint4*)((const char*)hin + ((size_t)cw0.x << 7) + lc * 16);
        uint4 hv1 = *(const uint4*)((const char*)hin + ((size_t)cw1.x << 7) + lc * 16);
        edge_fma(acc0, __uint_as_float(cw0.y), hv0);
        edge_fma(acc1, __uint_as_float(cw1.y), hv1);
    }
    for (; i < e; i += 8) {
        int idx = i + slot;
        uint2 cw = (idx < e) ? edges[idx] : make_uint2(0u, 0u);
        float wgt = (idx < e) ? __uint_as_float(cw.y) : 0.f;
        uint4 hv = *(const uint4*)((const char*)hin + ((size_t)cw.x << 7) + lc * 16);
        edge_fma(acc0, wgt, hv);
    }

    float r[8];
#pragma unroll
    for (int k = 0; k < 8; ++k) {
        float v = acc0[k] + acc1[k];
        v += __shfl_xor(v, 8, 64);
        v += __shfl_xor(v, 16, 64);
        v += __shfl_xor(v, 32, 64);
        r[k] = v;
    }

    size_t off = (size_t)wid * PAD_C + lc * 8;
    float4 h0a = *(const float4*)(h0f + off);
    float4 h0b4 = *(const float4*)(h0f + off + 4);
    r[0] = 0.9f * r[0] + 0.1f * h0a.x;  r[1] = 0.9f * r[1] + 0.1f * h0a.y;
    r[2] = 0.9f * r[2] + 0.1f * h0a.z;  r[3] = 0.9f * r[3] + 0.1f * h0a.w;
    r[4] = 0.9f * r[4] + 0.1f * h0b4.x; r[5] = 0.9f * r[5] + 0.1f * h0b4.y;
    r[6] = 0.9f * r[6] + 0.1f * h0b4.z; r[7] = 0.9f * r[7] + 0.1f * h0b4.w;

    if (!LAST) {
        if (slot == 0) {
            uint4 u;
            u.x = ((unsigned)f2bf(r[1]) << 16) | f2bf(r[0]);
            u.y = ((unsigned)f2bf(r[3]) << 16) | f2bf(r[2]);
            u.z = ((unsigned)f2bf(r[5]) << 16) | f2bf(r[4]);
            u.w = ((unsigned)f2bf(r[7]) << 16) | f2bf(r[6]);
            *(uint4*)((char*)hout_b + ((size_t)wid << 7) + lc * 16) = u;
        }
    } else {
        int ch0 = lc * 8;
        float m = -INFINITY;
#pragma unroll
        for (int k = 0; k < 8; ++k) if (ch0 + k < OUT_C) m = fmaxf(m, r[k]);
        m = fmaxf(m, __shfl_xor(m, 1, 64));
        m = fmaxf(m, __shfl_xor(m, 2, 64));
        m = fmaxf(m, __shfl_xor(m, 4, 64));
        float ss = 0.f;
#pragma unroll
        for (int k = 0; k < 8; ++k) if (ch0 + k < OUT_C) ss += __expf(r[k] - m);
        ss += __shfl_xor(ss, 1, 64);
        ss += __shfl_xor(ss, 2, 64);
        ss += __shfl_xor(ss, 4, 64);
        float lse = __logf(ss);
        if (slot == 0) {
#pragma unroll
            for (int k = 0; k < 8; ++k)
                if (ch0 + k < OUT_C)
                    out_f[(size_t)wid * OUT_C + ch0 + k] = (r[k] - m) - lse;
        }
    }
}

// ---------------------------------------------------------------------------
extern "C" void kernel_launch(void* const* d_in, const int* in_sizes, int n_in,
                              void* d_out, int out_size, void* d_ws, size_t ws_size,
                              hipStream_t stream) {
    const float* x    = (const float*)d_in[0];
    const int*   erow = (const int*)d_in[1];
    const int*   ecol = (const int*)d_in[2];
    const float* ew   = (const float*)d_in[3];
    const float* W1   = (const float*)d_in[4];
    const float* b1   = (const float*)d_in[5];
    const float* W2   = (const float*)d_in[6];
    const float* b2   = (const float*)d_in[7];
    float* out = (float*)d_out;

    char* p = (char*)d_ws;
    auto alloc = [&](size_t bytes) {
        char* r = p;
        p += (bytes + 255) & ~(size_t)255;
        return r;
    };
    char*  scratch = alloc((size_t)NBUCK * BCAP * 8);             // 16.1 MB (buckets / ha / hb)
    float* h0f    = (float*)alloc((size_t)N_NODES * PAD_C * 4);   // 12.8 MB
    unsigned short* h0b = (unsigned short*)alloc((size_t)N_NODES * PAD_C * 2); // 6.4 MB
    uint2* edges  = (uint2*)alloc((size_t)N_EDGES * 8);           // 12.8 MB packed CSR
    int*   rowptr = (int*)alloc((size_t)(N_NODES + 1) * 4);
    int*   bfill  = (int*)alloc((size_t)NBUCK * 4);
    int*   bbase  = (int*)alloc((size_t)(NBUCK + 1) * 4);
    float* bp     = (float*)alloc((size_t)PAD_C * 4);
    unsigned short* Wt  = (unsigned short*)alloc((size_t)HID_C * IN_C * 2);
    unsigned short* Wpt = (unsigned short*)alloc((size_t)PAD_C * HID_C * 2);
    // --- aliases onto scratch (sequential lifetimes, stream-ordered):
    uint2* buckets = (uint2*)scratch;                                       // CSR build
    unsigned short* ha = (unsigned short*)scratch;                          // 6.4 MB (prop)
    unsigned short* hb = (unsigned short*)(scratch + (size_t)N_NODES * PAD_C * 2); // 6.4 MB

    hipMemsetAsync(bfill, 0, (size_t)NBUCK * 4, stream);

    // CSR build (v3)
    bucket_scatter<<<PHB_BLOCKS, 256, 0, stream>>>(erow, ecol, ew, bfill, buckets);
    bucket_scan<<<1, 128, 0, stream>>>(bfill, bbase, rowptr);
    bucket_csr<<<NBUCK, 256, 0, stream>>>(buckets, bfill, bbase, rowptr, edges);

    // MLP (gemm2 fused into gemm1 epilogue; h_hid eliminated)
    transpose_w1<<<dim3(IN_C / 32, HID_C / 32), 256, 0, stream>>>(W1, Wt);
    pad_w2<<<(PAD_C * HID_C + 255) / 256, 256, 0, stream>>>(W2, b2, Wpt, bp);
    gemm1_fused<<<(N_NODES + 63) / 64, 256, 0, stream>>>(x, Wt, b1, Wpt, bp, h0f, h0b);

    // Propagation x10 (bf16 ping-pong; last layer fuses log_softmax -> out)
    const int prop_blocks = (N_NODES * 64 + 255) / 256;
    const unsigned short* cur = h0b;
    unsigned short* nxt = ha;
    for (int l = 0; l < NUM_LAYERS - 1; ++l) {
        prop8<false><<<prop_blocks, 256, 0, stream>>>(rowptr, edges, cur, h0f,
                                                      nxt, nullptr);
        const unsigned short* t = nxt;
        nxt = (nxt == ha) ? hb : ha;
        cur = t;
    }
    prop8<true><<<prop_blocks, 256, 0, stream>>>(rowptr, edges, cur, h0f,
                                                 nullptr, out);
}

// Round 5
// 624.622 us; speedup vs baseline: 1.0318x; 1.0318x over previous
//
#include <hip/hip_runtime.h>
#include <cstddef>
#include <cstdint>
#include <math.h>

#define N_NODES 50000
#define N_EDGES 1600000
#define IN_C 512
#define HID_C 256
#define OUT_C 50
#define PAD_C 64
#define NUM_LAYERS 10
#define NBUCK 98          // ceil(50000/512) row-buckets
#define BSHIFT 9          // 512 rows per bucket
#define BCAP 20480        // mean 16327 + 32 sigma — overflow unreachable
#define PHB_CHUNK 8192    // edges per block in bucket_scatter
#define PHB_BLOCKS 196    // ceil(N_EDGES / PHB_CHUNK)

typedef __attribute__((ext_vector_type(8))) short short8;    // 8 bf16 (4 VGPRs)
typedef __attribute__((ext_vector_type(4))) float floatx4;   // MFMA C/D frag

__device__ inline unsigned short f2bf(float f) {             // RNE fp32->bf16
    unsigned int u = __float_as_uint(f);
    u += 0x7fffu + ((u >> 16) & 1u);
    return (unsigned short)(u >> 16);
}

__device__ inline unsigned cvtpk(float lo, float hi) {       // 2xf32 -> packed bf16x2 (RNE)
    unsigned r;
    asm("v_cvt_pk_bf16_f32 %0, %1, %2" : "=v"(r) : "v"(lo), "v"(hi));
    return r;
}

__device__ inline short8 pack_bf16x8(float4 lo, float4 hi) {
    union { unsigned u[4]; short8 s; } r;
    r.u[0] = cvtpk(lo.x, lo.y);
    r.u[1] = cvtpk(lo.z, lo.w);
    r.u[2] = cvtpk(hi.x, hi.y);
    r.u[3] = cvtpk(hi.z, hi.w);
    return r.s;
}

// async 16B global->LDS (LDS dest is wave-uniform base + lane*16)
#define ASYNC16(g, l)                                                     \
    __builtin_amdgcn_global_load_lds(                                     \
        (const __attribute__((address_space(1))) void*)(g),               \
        (__attribute__((address_space(3))) void*)(l), 16, 0, 0)

#define WAITCNT6() asm volatile("s_waitcnt vmcnt(6)" ::: "memory")
#define WAITCNT0() asm volatile("s_waitcnt vmcnt(0)" ::: "memory")
#define SBAR()     __builtin_amdgcn_s_barrier()

// ---------------------------------------------------------------------------
// W1 [512,256] fp32  ->  Wt [256,512] bf16   (LDS-tiled transpose)
// ---------------------------------------------------------------------------
__global__ __launch_bounds__(256) void transpose_w1(const float* __restrict__ W1,
                                                    unsigned short* __restrict__ Wt) {
    __shared__ float tile[32][33];
    int bx = blockIdx.x;               // k-tile (16)
    int by = blockIdx.y;               // n-tile (8)
    int tx = threadIdx.x & 31, ty = threadIdx.x >> 5;   // 32 x 8
#pragma unroll
    for (int i = 0; i < 32; i += 8)
        tile[ty + i][tx] = W1[(bx * 32 + ty + i) * HID_C + by * 32 + tx];
    __syncthreads();
#pragma unroll
    for (int i = 0; i < 32; i += 8)
        Wt[(size_t)(by * 32 + ty + i) * IN_C + bx * 32 + tx] = f2bf(tile[tx][ty + i]);
}

// ---------------------------------------------------------------------------
// pad_w2: W2 [256,50] fp32 -> Wpt [64,256] bf16 TRANSPOSED, b2 -> bp[64]
// ---------------------------------------------------------------------------
__global__ void pad_w2(const float* __restrict__ W2, const float* __restrict__ b2,
                       unsigned short* __restrict__ Wpt, float* __restrict__ bp) {
    int idx = blockIdx.x * blockDim.x + threadIdx.x;
    if (idx < PAD_C * HID_C) {
        int n = idx >> 8, k = idx & 255;
        float v = (n < OUT_C) ? W2[k * OUT_C + n] : 0.f;
        Wpt[idx] = f2bf(v);
    }
    if (idx < PAD_C) bp[idx] = (idx < OUT_C) ? b2[idx] : 0.f;
}

// ---------------------------------------------------------------------------
// GEMM1+GEMM2 fused v3 — 3-buffer counted-vmcnt pipeline (T3/T4 minimal):
//  * A and B BOTH staged via coalesced global_load_lds (R4's per-lane A reads
//    were uncoalesced: 16 lanes x 16 different 2KB-strided rows -> 609 GB/s).
//  * 3 LDS buffers; per K-step: vmcnt(6) [buf ks landed; buf ks+1's 6 loads
//    stay in flight] -> s_barrier -> stage buf (ks+2)%3 [freed by THIS
//    barrier: last read at compute ks-1] -> compute buf ks%3.
//    ONE barrier/step, NO vmcnt(0) drain in loop, NO sched_barrier fences
//    (R2's fences = m141 order-pinning regression).
//  * Stage->use distance = 1.5 iterations: HBM latency hidden under compute.
//  * Loop fully unrolled so %3 indices constant-fold.
//  * B chunk-major (R4-verified conflict-free), A XOR-swizzled source
//    (R1-verified numerics).
// ---------------------------------------------------------------------------
__global__ __launch_bounds__(256) void gemm1_fused(const float* __restrict__ A,
                                                   const unsigned short* __restrict__ Wt,
                                                   const float* __restrict__ b1,
                                                   const unsigned short* __restrict__ Wpt,
                                                   const float* __restrict__ bp,
                                                   float* __restrict__ h0f,
                                                   unsigned short* __restrict__ h0b) {
    __shared__ __align__(16) char smem[73728];     // 3 x (8KB A + 16KB B)
    float*          Ab[3] = {(float*)smem,
                             (float*)(smem + 24576),
                             (float*)(smem + 49152)};
    unsigned short* Bb[3] = {(unsigned short*)(smem + 8192),
                             (unsigned short*)(smem + 32768),
                             (unsigned short*)(smem + 57344)};
    unsigned short* Hs = (unsigned short*)smem;    // [64][264] bf16, 33.8 KB (reused)
    const int HS_LD = 264;

    const int tid  = threadIdx.x;
    const int wave = tid >> 6, lane = tid & 63;
    const int quad = lane >> 4, l16 = lane & 15;
    const int m0 = blockIdx.x * 64;
    const int wm = (wave >> 1) * 32;               // row offset of this wave
    const int wn = (wave & 1) * 128;               // col offset of this wave

    floatx4 acc[2][8];
#pragma unroll
    for (int i = 0; i < 2; ++i)
#pragma unroll
        for (int j = 0; j < 8; ++j) acc[i][j] = (floatx4){0.f, 0.f, 0.f, 0.f};

    // per-thread staging coords (A: 2 slots of 512; B: 4 slots of 1024)
    const int ar = (tid >> 3), ac = tid & 7;       // slot j*256+tid -> r=slot>>3,c=slot&7
    // stage one BK=32 slab: A 64x32 fp32 (2 loads) + B 256x32 bf16 (4 loads)
    // = exactly 6 VMEM instructions per lane per stage (the vmcnt unit).
    auto stage = [&](int bi, int ks) {
        const int k0 = ks << 5;
#pragma unroll
        for (int j = 0; j < 2; ++j) {
            int slot = tid + j * 256;
            int r = slot >> 3, c = slot & 7;
            int gr = m0 + r;
            if (gr >= N_NODES) gr = N_NODES - 1;   // clamp: finite garbage, masked later
            const float* src = A + (size_t)gr * IN_C + k0 + ((c ^ (r & 7)) << 2);
            ASYNC16(src, Ab[bi] + (slot << 2));
        }
#pragma unroll
        for (int j = 0; j < 4; ++j) {              // chunk-major: slot = j*256 + tid
            const unsigned short* src = Wt + (size_t)tid * IN_C + k0 + (j << 3);
            ASYNC16(src, Bb[bi] + (j << 11) + (tid << 3));
        }
    };

    auto compute = [&](int bi) {
        const float* As_ = Ab[bi];
        const unsigned short* Bs_ = Bb[bi];
        short8 bfr[8], afr[2];
#pragma unroll
        for (int nt = 0; nt < 8; ++nt)
            bfr[nt] = *(const short8*)&Bs_[(quad << 11) + ((wn + nt * 16 + l16) << 3)];
#pragma unroll
        for (int mt = 0; mt < 2; ++mt) {
            int r  = wm + mt * 16 + l16;
            int rx = r & 7;
            float4 lo = *(const float4*)&As_[(r << 5) + (((2 * quad)     ^ rx) << 2)];
            float4 hi = *(const float4*)&As_[(r << 5) + (((2 * quad + 1) ^ rx) << 2)];
            afr[mt] = pack_bf16x8(lo, hi);
        }
#pragma unroll
        for (int mt = 0; mt < 2; ++mt)
#pragma unroll
            for (int nt = 0; nt < 8; ++nt)
                acc[mt][nt] = __builtin_amdgcn_mfma_f32_16x16x32_bf16(afr[mt], bfr[nt],
                                                                      acc[mt][nt], 0, 0, 0);
    };

    // --- pipelined main loop: 16 K-steps, 3 buffers, depth-2 prefetch ------
    stage(0, 0);
    stage(1, 1);
#pragma unroll
    for (int ks = 0; ks < 14; ++ks) {
        WAITCNT6();                    // buf ks%3 landed (only ks+1's 6 in flight)
        SBAR();                        // all waves: buf ks ready; buf (ks+2)%3 free
        stage((ks + 2) % 3, ks + 2);   // async; needed 2 iterations from now
        compute(ks % 3);
    }
    WAITCNT6(); SBAR(); compute(2);    // ks=14 (stage 15's loads = the 6 in flight)
    WAITCNT0(); SBAR(); compute(0);    // ks=15 (drain: no newer stages exist)
    __syncthreads();                   // full drain before Hs overlays buffers

    // --- stage relu(h + b1) to LDS bf16 (row = quad*4+r, col = l16 map) ----
#pragma unroll
    for (int nt = 0; nt < 8; ++nt) {
        int n = wn + nt * 16 + l16;
        float bn = b1[n];
#pragma unroll
        for (int mt = 0; mt < 2; ++mt)
#pragma unroll
            for (int r = 0; r < 4; ++r) {
                float v = acc[mt][nt][r] + bn;
                v = v > 0.f ? v : 0.f;
                Hs[(wm + mt * 16 + quad * 4 + r) * HS_LD + n] = f2bf(v);
            }
    }
    __syncthreads();

    // --- fused GEMM2: h0[64,64] = Hs[64,256] @ Wpt^T + bp ------------------
    floatx4 acc2[4];
#pragma unroll
    for (int nt = 0; nt < 4; ++nt) acc2[nt] = (floatx4){0.f, 0.f, 0.f, 0.f};
    const int hrow = (wave << 4) + l16;
#pragma unroll
    for (int k2 = 0; k2 < 8; ++k2) {
        short8 haf = *(const short8*)&Hs[hrow * HS_LD + (k2 << 5) + (quad << 3)];
#pragma unroll
        for (int nt = 0; nt < 4; ++nt) {
            short8 bf = *(const short8*)&Wpt[(size_t)((nt << 4) + l16) * HID_C + (k2 << 5) + (quad << 3)];
            acc2[nt] = __builtin_amdgcn_mfma_f32_16x16x32_bf16(haf, bf, acc2[nt], 0, 0, 0);
        }
    }
#pragma unroll
    for (int nt = 0; nt < 4; ++nt) {
        int c = (nt << 4) + l16;
        float bn = bp[c];
#pragma unroll
        for (int r = 0; r < 4; ++r) {
            int row = m0 + (wave << 4) + (quad << 2) + r;
            if (row < N_NODES) {
                float v = acc2[nt][r] + bn;
                h0f[(size_t)row * PAD_C + c] = v;
                h0b[(size_t)row * PAD_C + c] = f2bf(v);
            }
        }
    }
}

// ---------------------------------------------------------------------------
// CSR build v3 (R7-verified): bucket_scatter -> 98-scan -> fused per-bucket
// hist/scan/scatter. No global histogram, no global fill atomics.
// ---------------------------------------------------------------------------
__global__ __launch_bounds__(256) void bucket_scatter(const int* __restrict__ erow,
                                                      const int* __restrict__ ecol,
                                                      const float* __restrict__ ew,
                                                      int* __restrict__ bfill,
                                                      uint2* __restrict__ buckets) {
    __shared__ int lcnt[NBUCK];
    __shared__ int lbase[NBUCK];
    const int t = threadIdx.x;
    for (int b = t; b < NBUCK; b += 256) lcnt[b] = 0;
    __syncthreads();
    const int e0 = blockIdx.x * PHB_CHUNK;
    const int e1 = min(e0 + PHB_CHUNK, N_EDGES);
    for (int e = e0 + t; e < e1; e += 256)
        atomicAdd(&lcnt[erow[e] >> BSHIFT], 1);
    __syncthreads();
    for (int b = t; b < NBUCK; b += 256) {
        lbase[b] = atomicAdd(&bfill[b], lcnt[b]);
        lcnt[b] = 0;
    }
    __syncthreads();
    for (int e = e0 + t; e < e1; e += 256) {
        int r = erow[e];
        int b = r >> BSHIFT;
        int o = atomicAdd(&lcnt[b], 1);
        int idx = lbase[b] + o;
        if (idx < BCAP) {   // BCAP = mean + 32 sigma: always true
            unsigned packed = ((unsigned)(r - (b << BSHIFT)) << 17) | (unsigned)ecol[e];
            buckets[(size_t)b * BCAP + idx] = make_uint2(packed, __float_as_uint(ew[e]));
        }
    }
}

__global__ __launch_bounds__(128) void bucket_scan(const int* __restrict__ bfill,
                                                   int* __restrict__ bbase,
                                                   int* __restrict__ rowptr) {
    __shared__ int sd[128];
    int t = threadIdx.x;
    int v = (t < NBUCK) ? min(bfill[t], BCAP) : 0;
    sd[t] = v;
    __syncthreads();
    for (int off = 1; off < 128; off <<= 1) {
        int x = (t >= off) ? sd[t - off] : 0;
        __syncthreads();
        sd[t] += x;
        __syncthreads();
    }
    if (t < NBUCK) bbase[t] = sd[t] - v;
    if (t == NBUCK - 1) {
        bbase[NBUCK] = sd[t];
        rowptr[N_NODES] = sd[t];
    }
}

__global__ __launch_bounds__(256) void bucket_csr(const uint2* __restrict__ buckets,
                                                  const int* __restrict__ bfill,
                                                  const int* __restrict__ bbase,
                                                  int* __restrict__ rowptr,
                                                  uint2* __restrict__ edges) {
    __shared__ int hist[512];
    __shared__ int excl[512];
    __shared__ int psum[256];
    const int b = blockIdx.x;
    const int t = threadIdx.x;
    const int n = min(bfill[b], BCAP);
    const uint2* bk = buckets + (size_t)b * BCAP;

    hist[t] = 0; hist[t + 256] = 0;
    __syncthreads();
    for (int i = t; i < n; i += 256)
        atomicAdd(&hist[bk[i].x >> 17], 1);
    __syncthreads();
    int a0 = hist[2 * t], a1 = hist[2 * t + 1];
    psum[t] = a0 + a1;
    __syncthreads();
    for (int off = 1; off < 256; off <<= 1) {
        int x = (t >= off) ? psum[t - off] : 0;
        __syncthreads();
        psum[t] += x;
        __syncthreads();
    }
    int pe = psum[t] - (a0 + a1);
    excl[2 * t] = pe;
    excl[2 * t + 1] = pe + a0;
    __syncthreads();
    const int base = bbase[b];
#pragma unroll
    for (int k = 0; k < 2; ++k) {
        int lr = t + k * 256;
        int r = (b << BSHIFT) + lr;
        if (r < N_NODES) rowptr[r] = base + excl[lr];
    }
    hist[t] = 0; hist[t + 256] = 0;
    __syncthreads();
    for (int i = t; i < n; i += 256) {
        uint2 ed = bk[i];
        int lr = ed.x >> 17;
        int pos = base + excl[lr] + atomicAdd(&hist[lr], 1);
        edges[pos] = make_uint2(ed.x & 0x1FFFFu, ed.y);
    }
}

// ---------------------------------------------------------------------------
// Propagation v2: x4 unroll (4 independent 128B gathers in flight); 8 lanes x
// 16B cover one 128B row; xor(8/16/32) all-reduce; LAST fuses log_softmax.
// ---------------------------------------------------------------------------
__device__ inline void edge_fma(float* acc, float wgt, uint4 hv) {
    acc[0] = fmaf(wgt, __uint_as_float(hv.x << 16),         acc[0]);
    acc[1] = fmaf(wgt, __uint_as_float(hv.x & 0xffff0000u), acc[1]);
    acc[2] = fmaf(wgt, __uint_as_float(hv.y << 16),         acc[2]);
    acc[3] = fmaf(wgt, __uint_as_float(hv.y & 0xffff0000u), acc[3]);
    acc[4] = fmaf(wgt, __uint_as_float(hv.z << 16),         acc[4]);
    acc[5] = fmaf(wgt, __uint_as_float(hv.z & 0xffff0000u), acc[5]);
    acc[6] = fmaf(wgt, __uint_as_float(hv.w << 16),         acc[6]);
    acc[7] = fmaf(wgt, __uint_as_float(hv.w & 0xffff0000u), acc[7]);
}

template <bool LAST>
__global__ __launch_bounds__(256) void prop8(const int* __restrict__ rowptr,
                                             const uint2* __restrict__ edges,
                                             const unsigned short* __restrict__ hin,
                                             const float* __restrict__ h0f,
                                             unsigned short* __restrict__ hout_b,
                                             float* __restrict__ out_f) {
    int wid = (blockIdx.x * blockDim.x + threadIdx.x) >> 6;
    if (wid >= N_NODES) return;
    int lane = threadIdx.x & 63;
    int slot = lane >> 3;
    int lc   = lane & 7;
    int s = rowptr[wid], e = rowptr[wid + 1];

    float acc0[8], acc1[8];
#pragma unroll
    for (int k = 0; k < 8; ++k) { acc0[k] = 0.f; acc1[k] = 0.f; }

    int i = s;
    for (; i + 32 <= e; i += 32) {
        uint2 cw0 = edges[i + slot];
        uint2 cw1 = edges[i + 8 + slot];
        uint2 cw2 = edges[i + 16 + slot];
        uint2 cw3 = edges[i + 24 + slot];
        uint4 hv0 = *(const uint4*)((const char*)hin + ((size_t)cw0.x << 7) + lc * 16);
        uint4 hv1 = *(const uint4*)((const char*)hin + ((size_t)cw1.x << 7) + lc * 16);
        uint4 hv2 = *(const uint4*)((const char*)hin + ((size_t)cw2.x << 7) + lc * 16);
        uint4 hv3 = *(const uint4*)((const char*)hin + ((size_t)cw3.x << 7) + lc * 16);
        edge_fma(acc0, __uint_as_float(cw0.y), hv0);
        edge_fma(acc1, __uint_as_float(cw1.y), hv1);
        edge_fma(acc0, __uint_as_float(cw2.y), hv2);
        edge_fma(acc1, __uint_as_float(cw3.y), hv3);
    }
    for (; i + 16 <= e; i += 16) {
        uint2 cw0 = edges[i + slot];
        uint2 cw1 = edges[i + 8 + slot];
        uint4 hv0 = *(const uint4*)((const char*)hin + ((size_t)cw0.x << 7) + lc * 16);
        uint4 hv1 = *(const uint4*)((const char*)hin + ((size_t)cw1.x << 7) + lc * 16);
        edge_fma(acc0, __uint_as_float(cw0.y), hv0);
        edge_fma(acc1, __uint_as_float(cw1.y), hv1);
    }
    for (; i < e; i += 8) {
        int idx = i + slot;
        uint2 cw = (idx < e) ? edges[idx] : make_uint2(0u, 0u);
        float wgt = (idx < e) ? __uint_as_float(cw.y) : 0.f;
        uint4 hv = *(const uint4*)((const char*)hin + ((size_t)cw.x << 7) + lc * 16);
        edge_fma(acc0, wgt, hv);
    }

    float r[8];
#pragma unroll
    for (int k = 0; k < 8; ++k) {
        float v = acc0[k] + acc1[k];
        v += __shfl_xor(v, 8, 64);
        v += __shfl_xor(v, 16, 64);
        v += __shfl_xor(v, 32, 64);
        r[k] = v;
    }

    size_t off = (size_t)wid * PAD_C + lc * 8;
    float4 h0a = *(const float4*)(h0f + off);
    float4 h0b4 = *(const float4*)(h0f + off + 4);
    r[0] = 0.9f * r[0] + 0.1f * h0a.x;  r[1] = 0.9f * r[1] + 0.1f * h0a.y;
    r[2] = 0.9f * r[2] + 0.1f * h0a.z;  r[3] = 0.9f * r[3] + 0.1f * h0a.w;
    r[4] = 0.9f * r[4] + 0.1f * h0b4.x; r[5] = 0.9f * r[5] + 0.1f * h0b4.y;
    r[6] = 0.9f * r[6] + 0.1f * h0b4.z; r[7] = 0.9f * r[7] + 0.1f * h0b4.w;

    if (!LAST) {
        if (slot == 0) {
            uint4 u;
            u.x = ((unsigned)f2bf(r[1]) << 16) | f2bf(r[0]);
            u.y = ((unsigned)f2bf(r[3]) << 16) | f2bf(r[2]);
            u.z = ((unsigned)f2bf(r[5]) << 16) | f2bf(r[4]);
            u.w = ((unsigned)f2bf(r[7]) << 16) | f2bf(r[6]);
            *(uint4*)((char*)hout_b + ((size_t)wid << 7) + lc * 16) = u;
        }
    } else {
        int ch0 = lc * 8;
        float m = -INFINITY;
#pragma unroll
        for (int k = 0; k < 8; ++k) if (ch0 + k < OUT_C) m = fmaxf(m, r[k]);
        m = fmaxf(m, __shfl_xor(m, 1, 64));
        m = fmaxf(m, __shfl_xor(m, 2, 64));
        m = fmaxf(m, __shfl_xor(m, 4, 64));
        float ss = 0.f;
#pragma unroll
        for (int k = 0; k < 8; ++k) if (ch0 + k < OUT_C) ss += __expf(r[k] - m);
        ss += __shfl_xor(ss, 1, 64);
        ss += __shfl_xor(ss, 2, 64);
        ss += __shfl_xor(ss, 4, 64);
        float lse = __logf(ss);
        if (slot == 0) {
#pragma unroll
            for (int k = 0; k < 8; ++k)
                if (ch0 + k < OUT_C)
                    out_f[(size_t)wid * OUT_C + ch0 + k] = (r[k] - m) - lse;
        }
    }
}

// ---------------------------------------------------------------------------
extern "C" void kernel_launch(void* const* d_in, const int* in_sizes, int n_in,
                              void* d_out, int out_size, void* d_ws, size_t ws_size,
                              hipStream_t stream) {
    const float* x    = (const float*)d_in[0];
    const int*   erow = (const int*)d_in[1];
    const int*   ecol = (const int*)d_in[2];
    const float* ew   = (const float*)d_in[3];
    const float* W1   = (const float*)d_in[4];
    const float* b1   = (const float*)d_in[5];
    const float* W2   = (const float*)d_in[6];
    const float* b2   = (const float*)d_in[7];
    float* out = (float*)d_out;

    char* p = (char*)d_ws;
    auto alloc = [&](size_t bytes) {
        char* r = p;
        p += (bytes + 255) & ~(size_t)255;
        return r;
    };
    char*  scratch = alloc((size_t)NBUCK * BCAP * 8);             // 16.1 MB (buckets / ha / hb)
    float* h0f    = (float*)alloc((size_t)N_NODES * PAD_C * 4);   // 12.8 MB
    unsigned short* h0b = (unsigned short*)alloc((size_t)N_NODES * PAD_C * 2); // 6.4 MB
    uint2* edges  = (uint2*)alloc((size_t)N_EDGES * 8);           // 12.8 MB packed CSR
    int*   rowptr = (int*)alloc((size_t)(N_NODES + 1) * 4);
    int*   bfill  = (int*)alloc((size_t)NBUCK * 4);
    int*   bbase  = (int*)alloc((size_t)(NBUCK + 1) * 4);
    float* bp     = (float*)alloc((size_t)PAD_C * 4);
    unsigned short* Wt  = (unsigned short*)alloc((size_t)HID_C * IN_C * 2);
    unsigned short* Wpt = (unsigned short*)alloc((size_t)PAD_C * HID_C * 2);
    // --- aliases onto scratch (sequential lifetimes, stream-ordered):
    uint2* buckets = (uint2*)scratch;                                       // CSR build
    unsigned short* ha = (unsigned short*)scratch;                          // 6.4 MB (prop)
    unsigned short* hb = (unsigned short*)(scratch + (size_t)N_NODES * PAD_C * 2); // 6.4 MB

    hipMemsetAsync(bfill, 0, (size_t)NBUCK * 4, stream);

    // CSR build (v3)
    bucket_scatter<<<PHB_BLOCKS, 256, 0, stream>>>(erow, ecol, ew, bfill, buckets);
    bucket_scan<<<1, 128, 0, stream>>>(bfill, bbase, rowptr);
    bucket_csr<<<NBUCK, 256, 0, stream>>>(buckets, bfill, bbase, rowptr, edges);

    // MLP (gemm2 fused into gemm1 epilogue; h_hid eliminated)
    transpose_w1<<<dim3(IN_C / 32, HID_C / 32), 256, 0, stream>>>(W1, Wt);
    pad_w2<<<(PAD_C * HID_C + 255) / 256, 256, 0, stream>>>(W2, b2, Wpt, bp);
    gemm1_fused<<<(N_NODES + 63) / 64, 256, 0, stream>>>(x, Wt, b1, Wpt, bp, h0f, h0b);

    // Propagation x10 (bf16 ping-pong; last layer fuses log_softmax -> out)
    const int prop_blocks = (N_NODES * 64 + 255) / 256;
    const unsigned short* cur = h0b;
    unsigned short* nxt = ha;
    for (int l = 0; l < NUM_LAYERS - 1; ++l) {
        prop8<false><<<prop_blocks, 256, 0, stream>>>(rowptr, edges, cur, h0f,
                                                      nxt, nullptr);
        const unsigned short* t = nxt;
        nxt = (nxt == ha) ? hb : ha;
        cur = t;
    }
    prop8<true><<<prop_blocks, 256, 0, stream>>>(rowptr, edges, cur, h0f,
                                                 nullptr, out);
}